// Round 1
// baseline (590.230 us; speedup 1.0000x reference)
//
#include <hip/hip_runtime.h>
#include <hip/hip_bf16.h>
#include <math.h>

typedef unsigned short u16;
typedef __attribute__((ext_vector_type(8))) __bf16 bf16x8;
typedef __attribute__((ext_vector_type(4))) float f32x4;

__device__ inline u16 f2bf(float f) {
  union { float f; unsigned u; } x; x.f = f;
  unsigned r = x.u + 0x7fffu + ((x.u >> 16) & 1u);
  return (u16)(r >> 16);
}

__device__ inline void async16(const void* g, void* l) {
  __builtin_amdgcn_global_load_lds(
      (const __attribute__((address_space(1))) void*)g,
      (__attribute__((address_space(3))) void*)l, 16, 0, 0);
}

// ---------------- cast f32 -> bf16 (vectorized) ----------------
__global__ __launch_bounds__(256) void cast_bf16_kernel(
    const float* __restrict__ in, u16* __restrict__ out, int n4) {
  int i = blockIdx.x * 256 + threadIdx.x;
  if (i >= n4) return;
  float4 v = ((const float4*)in)[i];
  u16 o0 = f2bf(v.x), o1 = f2bf(v.y), o2 = f2bf(v.z), o3 = f2bf(v.w);
  unsigned lo = (unsigned)o0 | ((unsigned)o1 << 16);
  unsigned hi = (unsigned)o2 | ((unsigned)o3 << 16);
  ((uint2*)out)[i] = make_uint2(lo, hi);
}

// ---------------- V transpose: vt[b][d][s] = qkv[b][s][2176+d] ----------------
__global__ __launch_bounds__(256) void vt_kernel(
    const u16* __restrict__ qkv, u16* __restrict__ vt) {
  int idx = blockIdx.x * 256 + threadIdx.x;  // B*128*2048
  int s = idx & 2047;
  int d = (idx >> 11) & 127;
  int b = idx >> 18;
  vt[idx] = qkv[((size_t)b * 2048 + s) * 2304 + 2176 + d];
}

// ---------------- GEMM: C[M][N] = A[M][K] * W[N][K]^T + bias ----------------
// 128x128 tile, BK=64, 4 waves, global_load_lds staging with XOR-swizzled
// source so swizzled ds_read_b128 is bank-conflict-free (rule #21).
template <bool BF16OUT>
__global__ __launch_bounds__(256) void gemm_bt(
    const u16* __restrict__ A, const u16* __restrict__ Bw,
    const float* __restrict__ bias, void* __restrict__ Cout,
    int M, int N, int K) {
  __shared__ u16 As[128 * 64];
  __shared__ u16 Bs[128 * 64];
  const int t = threadIdx.x;
  const int w = t >> 6;
  const int lane = t & 63;
  const int lq = lane >> 4, lr = lane & 15;
  const long brow = (long)blockIdx.y * 128;
  const long bcol = (long)blockIdx.x * 128;
  const int wr = (w >> 1) * 64, wc = (w & 1) * 64;
  f32x4 acc[4][4] = {};

  int rA[4], cA[4];
#pragma unroll
  for (int it = 0; it < 4; ++it) {
    int ci = it * 256 + t;
    rA[it] = ci >> 3;                 // tile row (0..127)
    cA[it] = (ci & 7) ^ (rA[it] & 7); // swizzled source 16B-chunk in row
  }

  for (int kt = 0; kt < K; kt += 64) {
#pragma unroll
    for (int it = 0; it < 4; ++it) {
      const u16* srcA = A + (brow + rA[it]) * (long)K + kt + cA[it] * 8;
      async16(srcA, (char*)As + (it * 256 + w * 64) * 16);
      const u16* srcB = Bw + (bcol + rA[it]) * (long)K + kt + cA[it] * 8;
      async16(srcB, (char*)Bs + (it * 256 + w * 64) * 16);
    }
    __syncthreads();
#pragma unroll
    for (int kb = 0; kb < 2; ++kb) {
      bf16x8 af[4], bfr[4];
#pragma unroll
      for (int m = 0; m < 4; ++m) {
        int row = wr + m * 16 + lr;
        int byte = (row * 128 + kb * 64 + lq * 16) ^ ((row & 7) << 4);
        af[m] = *(const bf16x8*)((const char*)As + byte);
      }
#pragma unroll
      for (int n = 0; n < 4; ++n) {
        int row = wc + n * 16 + lr;
        int byte = (row * 128 + kb * 64 + lq * 16) ^ ((row & 7) << 4);
        bfr[n] = *(const bf16x8*)((const char*)Bs + byte);
      }
#pragma unroll
      for (int m = 0; m < 4; ++m)
#pragma unroll
        for (int n = 0; n < 4; ++n)
          acc[m][n] = __builtin_amdgcn_mfma_f32_16x16x32_bf16(
              af[m], bfr[n], acc[m][n], 0, 0, 0);
    }
    __syncthreads();
  }

#pragma unroll
  for (int m = 0; m < 4; ++m) {
    long row0 = brow + wr + m * 16 + lq * 4;
#pragma unroll
    for (int n = 0; n < 4; ++n) {
      long col = bcol + wc + n * 16 + lr;
      float bv = bias[col];
#pragma unroll
      for (int j = 0; j < 4; ++j) {
        float v = acc[m][n][j] + bv;
        if (BF16OUT)
          ((u16*)Cout)[(row0 + j) * N + col] = f2bf(v);
        else
          ((float*)Cout)[(row0 + j) * N + col] = v;
      }
    }
  }
}

// ---------------- Flash attention (MQA, causal) ----------------
// 1 wave per 16 q-rows. KV tiles of 32. Online softmax in f32.
__global__ __launch_bounds__(64) void attn_kernel(
    const u16* __restrict__ qkv, const u16* __restrict__ vt,
    u16* __restrict__ ctx) {
  const int lane = threadIdx.x;
  const int lq = lane >> 4, lr = lane & 15;
  const int bid = blockIdx.x;
  const int qt = bid & 127;
  const int h = (bid >> 7) & 15;
  const int b = bid >> 11;
  const int s0 = qt * 16;
  const size_t qb = (size_t)b * 2048 * 2304;

  bf16x8 qf[4];
#pragma unroll
  for (int kc = 0; kc < 4; ++kc)
    qf[kc] = *(const bf16x8*)(qkv + qb + (size_t)(s0 + lr) * 2304 + h * 128 +
                              kc * 32 + lq * 8);

  float mrow[4] = {-INFINITY, -INFINITY, -INFINITY, -INFINITY};
  float lrow[4] = {0.f, 0.f, 0.f, 0.f};
  f32x4 o[8] = {};
  __shared__ u16 Pl[16][72];  // 144B row stride: 16B-aligned, 2-way banks max

  const int ntiles = (s0 + 15) / 32 + 1;
  const float scale = 0.08838834764831845f;
  for (int j2 = 0; j2 < ntiles; ++j2) {
    const int kvb = j2 * 32;
    f32x4 sc[2] = {};
#pragma unroll
    for (int g = 0; g < 2; ++g) {
      const u16* kbase = qkv + qb + (size_t)(kvb + g * 16 + lr) * 2304 + 2048;
#pragma unroll
      for (int kc = 0; kc < 4; ++kc) {
        bf16x8 kf = *(const bf16x8*)(kbase + kc * 32 + lq * 8);
        sc[g] = __builtin_amdgcn_mfma_f32_16x16x32_bf16(qf[kc], kf, sc[g],
                                                        0, 0, 0);
      }
    }
#pragma unroll
    for (int r = 0; r < 4; ++r) {
      const int qi = s0 + lq * 4 + r;
      float v0 = sc[0][r] * scale;
      float v1 = sc[1][r] * scale;
      if (kvb + lr > qi) v0 = -INFINITY;
      if (kvb + 16 + lr > qi) v1 = -INFINITY;
      float mx = fmaxf(v0, v1);
#pragma unroll
      for (int d = 8; d >= 1; d >>= 1) mx = fmaxf(mx, __shfl_xor(mx, d));
      float mn = fmaxf(mrow[r], mx);
      float alpha = __expf(mrow[r] - mn);
      float p0 = __expf(v0 - mn);
      float p1 = __expf(v1 - mn);
      float rs = p0 + p1;
#pragma unroll
      for (int d = 8; d >= 1; d >>= 1) rs += __shfl_xor(rs, d);
      lrow[r] = lrow[r] * alpha + rs;
      mrow[r] = mn;
#pragma unroll
      for (int n = 0; n < 8; ++n) o[n][r] *= alpha;
      Pl[lq * 4 + r][lr] = f2bf(p0);
      Pl[lq * 4 + r][16 + lr] = f2bf(p1);
    }
    __syncthreads();
    bf16x8 pa = *(const bf16x8*)(&Pl[lr][lq * 8]);
    const u16* vb = vt + ((size_t)b * 128 + lr) * 2048 + kvb + lq * 8;
#pragma unroll
    for (int n = 0; n < 8; ++n) {
      bf16x8 vf = *(const bf16x8*)(vb + (size_t)n * 16 * 2048);
      o[n] = __builtin_amdgcn_mfma_f32_16x16x32_bf16(pa, vf, o[n], 0, 0, 0);
    }
    __syncthreads();  // Pl reads done before next tile overwrites
  }

#pragma unroll
  for (int r = 0; r < 4; ++r) {
    float inv = 1.f / lrow[r];
    size_t rowoff = ((size_t)b * 2048 + s0 + lq * 4 + r) * 2048 + h * 128;
#pragma unroll
    for (int n = 0; n < 8; ++n)
      ctx[rowoff + n * 16 + lr] = f2bf(o[n][r] * inv);
  }
}

extern "C" void kernel_launch(void* const* d_in, const int* in_sizes, int n_in,
                              void* d_out, int out_size, void* d_ws,
                              size_t ws_size, hipStream_t stream) {
  (void)in_sizes; (void)n_in; (void)out_size; (void)ws_size;
  const float* hs = (const float*)d_in[0];
  const float* attn_w = (const float*)d_in[1];
  const float* attn_b = (const float*)d_in[2];
  const float* proj_w = (const float*)d_in[3];
  const float* proj_b = (const float*)d_in[4];
  float* out = (float*)d_out;

  u16* hs_b = (u16*)d_ws;                      // 4096*2048
  u16* aw_b = hs_b + (size_t)4096 * 2048;      // 2304*2048
  u16* pw_b = aw_b + (size_t)2304 * 2048;      // 2048*2048
  u16* qkv_b = pw_b + (size_t)2048 * 2048;     // 4096*2304
  u16* vt_b = qkv_b + (size_t)4096 * 2304;     // 2*128*2048
  u16* ctx_b = vt_b + (size_t)2 * 128 * 2048;  // 4096*2048

  cast_bf16_kernel<<<8192, 256, 0, stream>>>(hs, hs_b, 2097152);
  cast_bf16_kernel<<<4608, 256, 0, stream>>>(attn_w, aw_b, 1179648);
  cast_bf16_kernel<<<4096, 256, 0, stream>>>(proj_w, pw_b, 1048576);

  gemm_bt<true><<<dim3(18, 32), 256, 0, stream>>>(hs_b, aw_b, attn_b, qkv_b,
                                                  4096, 2304, 2048);
  vt_kernel<<<2048, 256, 0, stream>>>(qkv_b, vt_b);
  attn_kernel<<<4096, 64, 0, stream>>>(qkv_b, vt_b, ctx_b);
  gemm_bt<false><<<dim3(16, 32), 256, 0, stream>>>(ctx_b, pw_b, proj_b, out,
                                                   4096, 2048, 2048);
}